// Round 2
// baseline (460.421 us; speedup 1.0000x reference)
//
#include <hip/hip_runtime.h>
#include <math.h>

// Problem constants
#define Nn   1000
#define FIN  64
#define FOUT 128
#define Lc   64      // T*B

// ws float-offsets
#define OFF_DEG    0        // 1024 floats: atomic counts -> dinv (in place)
#define OFF_FILL   1024     // 1024 ints
#define OFF_FLAG   2048     // 1 int  (1 = edge_index is int64)
#define OFF_ROWPTR 3072     // 1001 ints
#define OFF_CSCOL  16384    // E ints
#define OFF_CSW    28672    // E floats
#define OFF_WCAT   40960    // [128][256]  (z|h gate weights, xg|agg rows)
#define OFF_BC     73728    // [256]       bx[g]+bh[g]
#define OFF_WTIN   73984    // [128][384]  w_in^T
#define OFF_WTOUT  123136   // [128][128]  w_out^T
#define OFF_XGAT   147456   // [1000][128][64]  xg (f<64) | agg (f>=64), transposed [f][l]

__global__ void k_detect(const void* edge, int* flag) {
  const long long* p = (const long long*)edge;
  int ok = 1;
  for (int i = 0; i < 16; ++i) { long long v = p[i]; if (v < 0 || v >= Nn) ok = 0; }
  *flag = ok;
}

__device__ __forceinline__ int edge_at(const void* edge, int idx, int fl) {
  return fl ? (int)((const long long*)edge)[idx] : ((const int*)edge)[idx];
}

__global__ void k_deg(const void* edge, int E, const int* flag, float* degf) {
  int e = blockIdx.x * 256 + threadIdx.x;
  if (e >= E) return;
  int r = edge_at(edge, e, *flag);
  atomicAdd(degf + r, 1.0f);
}

__global__ void k_scan(const float* degf, int* rowptr) {
  __shared__ int sc[1024];
  int tid = threadIdx.x;
  sc[tid] = (tid < Nn) ? (int)degf[tid] : 0;
  __syncthreads();
  for (int off = 1; off < 1024; off <<= 1) {
    int t = (tid >= off) ? sc[tid - off] : 0;
    __syncthreads();
    sc[tid] += t;
    __syncthreads();
  }
  if (tid == 0) rowptr[0] = 0;
  if (tid < Nn) rowptr[tid + 1] = sc[tid];
}

__global__ void k_dinv(float* degf) {
  int n = blockIdx.x * 256 + threadIdx.x;
  if (n >= Nn) return;
  float c = degf[n];
  degf[n] = (c > 0.f) ? (1.0f / sqrtf(c)) : 0.f;
}

__global__ void k_scatter(const void* edge, int E, const int* flag, const float* dinv,
                          const int* rowptr, int* fill, int* cs_col, float* cs_w) {
  int e = blockIdx.x * 256 + threadIdx.x;
  if (e >= E) return;
  int fl = *flag;
  int r = edge_at(edge, e, fl);
  int c = edge_at(edge, E + e, fl);
  int pos = rowptr[r] + atomicAdd(fill + r, 1);
  cs_col[pos] = c;
  cs_w[pos] = dinv[r] * dinv[c];
}

__global__ void k_wprep(const float* wx0, const float* wx1, const float* bx, const float* bh,
                        const float* w_in, const float* w_out, float* ws) {
  int idx = blockIdx.x * 256 + threadIdx.x;
  if (idx < 32768) {                      // Wcat[f][j], f in [0,128), j in [0,256)
    int f = idx >> 8, j = idx & 255;
    int g = (j < 128) ? 0 : 2, jj = j & 127;
    float v = (f < 64) ? wx0[(g * 64 + f) * 128 + jj]
                       : wx1[(g * 64 + (f - 64)) * 128 + jj];
    ws[OFF_WCAT + idx] = v;
    return;
  }
  idx -= 32768;
  if (idx < 256) {                        // bc[j] = bx[g] + bh[g]
    int g = (idx < 128) ? 0 : 2, jj = idx & 127;
    ws[OFF_BC + idx] = bx[g * 128 + jj] + bh[g * 128 + jj];
    return;
  }
  idx -= 256;
  if (idx < 49152) {                      // w_in^T [128][384]
    int f = idx / 384, j = idx % 384;
    ws[OFF_WTIN + idx] = w_in[j * 128 + f];
    return;
  }
  idx -= 49152;
  if (idx < 16384) {                      // w_out^T [128][128]
    int f = idx >> 7, j = idx & 127;
    ws[OFF_WTOUT + idx] = w_out[j * 128 + f];
  }
}

// x[b][t][n][f] -> xgaT[n][f][l], l = t*4+b
__global__ void k_xT(const float* __restrict__ x, float* __restrict__ xgaT) {
  int idx = blockIdx.x * 256 + threadIdx.x;       // N*64*64 = 4,096,000
  int n = idx >> 12;
  int rem = idx & 4095;                           // f*64 + l
  int f = rem >> 6, l = rem & 63;
  int b = l & 3, t = l >> 2;
  xgaT[(n << 13) + rem] = x[((b * 16 + t) * 1000 + n) * 64 + f];
}

// agg[n][f][l] = sum over CSR edges of row n: w * xg[col][f][l]  -> xgaT[n][64+f][l]
__global__ void k_agg(float* xgaT, const int* __restrict__ rowptr,
                      const int* __restrict__ cs_col, const float* __restrict__ cs_w) {
  int n = blockIdx.x;
  int tid = threadIdx.x;
  int l4 = tid & 15, f0 = tid >> 4;               // f = f0 + 16*i
  float4 acc[4];
  #pragma unroll
  for (int i = 0; i < 4; ++i) { acc[i].x = 0.f; acc[i].y = 0.f; acc[i].z = 0.f; acc[i].w = 0.f; }
  int kb = rowptr[n], ke = rowptr[n + 1];
  for (int k = kb; k < ke; ++k) {
    int c = cs_col[k];
    float w = cs_w[k];
    #pragma unroll
    for (int i = 0; i < 4; ++i) {
      int f = f0 + 16 * i;
      float4 v = *reinterpret_cast<const float4*>(xgaT + (c * 128 + f) * 64 + l4 * 4);
      acc[i].x = fmaf(w, v.x, acc[i].x);
      acc[i].y = fmaf(w, v.y, acc[i].y);
      acc[i].z = fmaf(w, v.z, acc[i].z);
      acc[i].w = fmaf(w, v.w, acc[i].w);
    }
  }
  #pragma unroll
  for (int i = 0; i < 4; ++i) {
    int f = f0 + 16 * i;
    *reinterpret_cast<float4*>(xgaT + (n * 128 + 64 + f) * 64 + l4 * 4) = acc[i];
  }
}

// Fused per-node: gate GEMM -> GRU -> qkv -> attention -> out projection.
// LDS: R_XQ (xaT then qT), R_A (aT then ctxT), R_K, R_V : 4 x 32KB = 128KB.
__global__ __launch_bounds__(256, 1)
void k_fused(const float* __restrict__ ws, float* __restrict__ out,
             const float* __restrict__ b_in, const float* __restrict__ b_out) {
  extern __shared__ float lds[];
  float* R_XQ = lds;
  float* R_A  = lds + 8192;
  float* R_K  = lds + 16384;
  float* R_V  = lds + 24576;
  const int n = blockIdx.x;
  const int tid = threadIdx.x;

  { // stage xgaT[n] ([128][64], already transposed) into LDS
    const float4* src = reinterpret_cast<const float4*>(ws + OFF_XGAT + n * 8192);
    float4* dst = reinterpret_cast<float4*>(R_XQ);
    #pragma unroll
    for (int i = 0; i < 8; ++i) dst[tid + i * 256] = src[tid + i * 256];
  }
  __syncthreads();

  { // gate GEMM [64 rows][z:128|h:128 cols], K=128; GRU epilogue -> R_A = aT[j][l']
    const int ty = tid >> 5, tx = tid & 31;
    const int r0 = ty * 8, j0 = tx * 4;
    const float* Wc = ws + OFF_WCAT;
    float accz[8][4], acch[8][4];
    {
      const float4 bz = *reinterpret_cast<const float4*>(ws + OFF_BC + j0);
      const float4 bhh = *reinterpret_cast<const float4*>(ws + OFF_BC + 128 + j0);
      const float bzv[4] = {bz.x, bz.y, bz.z, bz.w};
      const float bhv[4] = {bhh.x, bhh.y, bhh.z, bhh.w};
      #pragma unroll
      for (int r = 0; r < 8; ++r)
        #pragma unroll
        for (int c = 0; c < 4; ++c) { accz[r][c] = bzv[c]; acch[r][c] = bhv[c]; }
    }
    #pragma unroll 4
    for (int f = 0; f < 128; ++f) {
      const float4 a0 = reinterpret_cast<const float4*>(R_XQ + f * 64 + r0)[0];
      const float4 a1 = reinterpret_cast<const float4*>(R_XQ + f * 64 + r0)[1];
      const float4 wz = *reinterpret_cast<const float4*>(Wc + f * 256 + j0);
      const float4 wh = *reinterpret_cast<const float4*>(Wc + f * 256 + 128 + j0);
      const float av[8] = {a0.x, a0.y, a0.z, a0.w, a1.x, a1.y, a1.z, a1.w};
      const float wzv[4] = {wz.x, wz.y, wz.z, wz.w};
      const float whv[4] = {wh.x, wh.y, wh.z, wh.w};
      #pragma unroll
      for (int r = 0; r < 8; ++r)
        #pragma unroll
        for (int c = 0; c < 4; ++c) {
          accz[r][c] = fmaf(av[r], wzv[c], accz[r][c]);
          acch[r][c] = fmaf(av[r], whv[c], acch[r][c]);
        }
    }
    #pragma unroll
    for (int r = 0; r < 8; ++r) {
      const int l = r0 + r;
      const int lp = (l & 3) * 16 + (l >> 2);   // l = t*4+b -> l' = b*16+t
      #pragma unroll
      for (int c = 0; c < 4; ++c) {
        const float z = 1.0f / (1.0f + __expf(-accz[r][c]));
        const float hn = (1.0f - z) * tanhf(acch[r][c]);
        R_A[(j0 + c) * 64 + lp] = hn;
      }
    }
  }
  __syncthreads();

  { // qkv GEMM: [64 rows][384 cols], K=128; q -> R_XQ (qT[j][l]), k/v row-major
    const int ry = tid >> 5, tx = tid & 31;
    const int r0 = ry * 8;
    const int j0 = tx * 12;
    const float* wT = ws + OFF_WTIN;
    float acc[12][8];
    #pragma unroll
    for (int cc = 0; cc < 3; ++cc) {
      const float4 bv = *reinterpret_cast<const float4*>(b_in + j0 + cc * 4);
      const float bb[4] = {bv.x, bv.y, bv.z, bv.w};
      #pragma unroll
      for (int c = 0; c < 4; ++c)
        #pragma unroll
        for (int r = 0; r < 8; ++r) acc[cc * 4 + c][r] = bb[c];
    }
    #pragma unroll 2
    for (int f = 0; f < 128; ++f) {
      const float4 a0 = reinterpret_cast<const float4*>(R_A + f * 64 + r0)[0];
      const float4 a1 = reinterpret_cast<const float4*>(R_A + f * 64 + r0)[1];
      const float av[8] = {a0.x, a0.y, a0.z, a0.w, a1.x, a1.y, a1.z, a1.w};
      #pragma unroll
      for (int cc = 0; cc < 3; ++cc) {
        const float4 wv = *reinterpret_cast<const float4*>(wT + f * 384 + j0 + cc * 4);
        const float wvv[4] = {wv.x, wv.y, wv.z, wv.w};
        #pragma unroll
        for (int c = 0; c < 4; ++c)
          #pragma unroll
          for (int r = 0; r < 8; ++r)
            acc[cc * 4 + c][r] = fmaf(av[r], wvv[c], acc[cc * 4 + c][r]);
      }
    }
    #pragma unroll
    for (int cc = 0; cc < 3; ++cc) {
      const int jb = j0 + cc * 4;
      const int sec = jb >> 7;
      const int jj = jb & 127;
      if (sec == 0) {
        #pragma unroll
        for (int c = 0; c < 4; ++c)
          #pragma unroll
          for (int r = 0; r < 8; ++r)
            R_XQ[(jj + c) * 64 + r0 + r] = acc[cc * 4 + c][r];
      } else {
        float* dst = (sec == 1) ? R_K : R_V;
        #pragma unroll
        for (int r = 0; r < 8; ++r) {
          float4 v;
          v.x = acc[cc * 4 + 0][r]; v.y = acc[cc * 4 + 1][r];
          v.z = acc[cc * 4 + 2][r]; v.w = acc[cc * 4 + 3][r];
          *reinterpret_cast<float4*>(dst + (r0 + r) * 128 + jj) = v;
        }
      }
    }
  }
  __syncthreads();

  { // attention: wave = head, lane = query row; softmax fully in-lane
    const int h = tid >> 6, l = tid & 63;
    float q[32];
    #pragma unroll
    for (int d = 0; d < 32; ++d)
      q[d] = R_XQ[(h * 32 + d) * 64 + l] * 0.17677669529663687f; // 1/sqrt(32)
    float s[64];
    #pragma unroll
    for (int m = 0; m < 64; ++m) {
      float p0 = 0.f, p1 = 0.f, p2 = 0.f, p3 = 0.f;
      const float4* kr = reinterpret_cast<const float4*>(R_K + m * 128 + h * 32);
      #pragma unroll
      for (int i = 0; i < 8; ++i) {
        const float4 kv = kr[i];
        p0 = fmaf(q[i * 4 + 0], kv.x, p0);
        p1 = fmaf(q[i * 4 + 1], kv.y, p1);
        p2 = fmaf(q[i * 4 + 2], kv.z, p2);
        p3 = fmaf(q[i * 4 + 3], kv.w, p3);
      }
      s[m] = (p0 + p1) + (p2 + p3);
    }
    float mx = s[0];
    #pragma unroll
    for (int m = 1; m < 64; ++m) mx = fmaxf(mx, s[m]);
    float s0 = 0.f, s1 = 0.f, s2 = 0.f, s3 = 0.f;
    #pragma unroll
    for (int m = 0; m < 64; m += 4) {
      s[m]     = __expf(s[m]     - mx); s0 += s[m];
      s[m + 1] = __expf(s[m + 1] - mx); s1 += s[m + 1];
      s[m + 2] = __expf(s[m + 2] - mx); s2 += s[m + 2];
      s[m + 3] = __expf(s[m + 3] - mx); s3 += s[m + 3];
    }
    const float inv = 1.0f / ((s0 + s1) + (s2 + s3));
    float c[32];
    #pragma unroll
    for (int d = 0; d < 32; ++d) c[d] = 0.f;
    #pragma unroll
    for (int m = 0; m < 64; ++m) {
      const float p = s[m];
      const float4* vr = reinterpret_cast<const float4*>(R_V + m * 128 + h * 32);
      #pragma unroll
      for (int i = 0; i < 8; ++i) {
        const float4 vv = vr[i];
        c[i * 4 + 0] = fmaf(p, vv.x, c[i * 4 + 0]);
        c[i * 4 + 1] = fmaf(p, vv.y, c[i * 4 + 1]);
        c[i * 4 + 2] = fmaf(p, vv.z, c[i * 4 + 2]);
        c[i * 4 + 3] = fmaf(p, vv.w, c[i * 4 + 3]);
      }
    }
    #pragma unroll
    for (int d = 0; d < 32; ++d)
      R_A[(h * 32 + d) * 64 + l] = c[d] * inv;   // ctxT[f][l]
  }
  __syncthreads();

  { // out projection: [64 rows][128 cols], K=128
    const int ry = tid >> 5, tx = tid & 31;
    const int r0 = ry * 8, j0 = tx * 4;
    const float* wT = ws + OFF_WTOUT;
    float acc[8][4];
    {
      const float4 bo = *reinterpret_cast<const float4*>(b_out + j0);
      const float bb[4] = {bo.x, bo.y, bo.z, bo.w};
      #pragma unroll
      for (int r = 0; r < 8; ++r)
        #pragma unroll
        for (int c = 0; c < 4; ++c) acc[r][c] = bb[c];
    }
    #pragma unroll 4
    for (int f = 0; f < 128; ++f) {
      const float4 a0 = reinterpret_cast<const float4*>(R_A + f * 64 + r0)[0];
      const float4 a1 = reinterpret_cast<const float4*>(R_A + f * 64 + r0)[1];
      const float4 wv = *reinterpret_cast<const float4*>(wT + f * 128 + j0);
      const float av[8] = {a0.x, a0.y, a0.z, a0.w, a1.x, a1.y, a1.z, a1.w};
      const float wvv[4] = {wv.x, wv.y, wv.z, wv.w};
      #pragma unroll
      for (int r = 0; r < 8; ++r)
        #pragma unroll
        for (int c = 0; c < 4; ++c)
          acc[r][c] = fmaf(av[r], wvv[c], acc[r][c]);
    }
    #pragma unroll
    for (int r = 0; r < 8; ++r) {
      float4 v;
      v.x = acc[r][0]; v.y = acc[r][1]; v.z = acc[r][2]; v.w = acc[r][3];
      *reinterpret_cast<float4*>(out + ((r0 + r) * 1000 + n) * 128 + j0) = v;
    }
  }
}

extern "C" void kernel_launch(void* const* d_in, const int* in_sizes, int n_in,
                              void* d_out, int out_size, void* d_ws, size_t ws_size,
                              hipStream_t stream) {
  const float* x     = (const float*)d_in[0];
  const void*  edge  = d_in[1];
  const float* wx0   = (const float*)d_in[2];
  const float* wx1   = (const float*)d_in[3];
  const float* bx    = (const float*)d_in[4];
  const float* bh    = (const float*)d_in[7];
  const float* w_in  = (const float*)d_in[8];
  const float* b_in  = (const float*)d_in[9];
  const float* w_out = (const float*)d_in[10];
  const float* b_out = (const float*)d_in[11];
  float* out = (float*)d_out;
  float* ws  = (float*)d_ws;
  int*   wsi = (int*)d_ws;
  const int E = in_sizes[1] / 2;

  (void)hipFuncSetAttribute((const void*)k_fused,
                            hipFuncAttributeMaxDynamicSharedMemorySize, 131072);

  // zero deg counts + fill counters
  hipMemsetAsync(d_ws, 0, 2048 * sizeof(float), stream);

  k_detect<<<1, 1, 0, stream>>>(edge, wsi + OFF_FLAG);
  k_deg<<<(E + 255) / 256, 256, 0, stream>>>(edge, E, wsi + OFF_FLAG, ws + OFF_DEG);
  k_scan<<<1, 1024, 0, stream>>>(ws + OFF_DEG, wsi + OFF_ROWPTR);
  k_dinv<<<4, 256, 0, stream>>>(ws + OFF_DEG);
  k_scatter<<<(E + 255) / 256, 256, 0, stream>>>(edge, E, wsi + OFF_FLAG, ws + OFF_DEG,
                                                 wsi + OFF_ROWPTR, wsi + OFF_FILL,
                                                 wsi + OFF_CSCOL, ws + OFF_CSW);
  k_wprep<<<385, 256, 0, stream>>>(wx0, wx1, bx, bh, w_in, w_out, ws);
  k_xT<<<16000, 256, 0, stream>>>(x, ws + OFF_XGAT);
  k_agg<<<1000, 256, 0, stream>>>(ws + OFF_XGAT, wsi + OFF_ROWPTR,
                                  wsi + OFF_CSCOL, ws + OFF_CSW);
  k_fused<<<1000, 256, 131072, stream>>>(ws, out, b_in, b_out);
}